// Round 2
// baseline (425.706 us; speedup 1.0000x reference)
//
#include <hip/hip_runtime.h>
#include <stdint.h>

// Cost volume = 48-wide band of Gram matrix L^T R per (b,h), K = c = 128.
// bf16 MFMA 32x32x16. Memory-bound target ~47us (298 MB @ 6.3 TB/s).
// R2: register-prefetch pipeline + c-pair LDS layout (b32 frag reads) +
//     40KB LDS (3-pass epilogue) + NT output stores.

typedef __bf16 bf16x8 __attribute__((ext_vector_type(8)));
typedef float floatx16 __attribute__((ext_vector_type(16)));

constexpr int W = 320, H = 96, C = 128, NB = 8, MAXD = 48;
constexpr int HW = H * W;        // 30720
constexpr int KC = 32;           // c per chunk
constexpr int CP = KC / 2;       // pair-rows per chunk = 16
constexpr int MATD = CP * W;     // dwords per staged matrix = 5120

__device__ __forceinline__ uint32_t pack_bf16x2(float a, float b) {
    // RNE f32->bf16, (a -> low16, b -> high16). dword (cpair*W + x) holds
    // (c,x) in low half, (c+1,x) in high half == MFMA k-order.
    uint32_t ua = __float_as_uint(a), ub = __float_as_uint(b);
    uint32_t lo = (ua + 0x7fffu + ((ua >> 16) & 1u)) >> 16;
    uint32_t hi = (ub + 0x7fffu + ((ub >> 16) & 1u)) & 0xffff0000u;
    return hi | lo;
}

__global__ __launch_bounds__(640, 5) void cost_volume_kernel(
    const float* __restrict__ Lg, const float* __restrict__ Rg,
    float* __restrict__ out)
{
    // 40960 B: bf16 staging [16 c-pairs][320 x] x2 matrices; reused by the
    // per-wave epilogue scratch (10 waves * 16*33 f32 = 21120 B).
    __shared__ uint32_t lds[2 * MATD];

    const int t    = threadIdx.x;
    const int lane = t & 63;
    const int p    = t >> 6;       // wave id = 32-wide x-tile id
    const int n    = lane & 31;
    const int half = lane >> 5;

    const int b = blockIdx.x / H;
    const int h = blockIdx.x % H;
    const int baseLR = b * (C * HW) + h * W;

    // staging unit: thread t covers c-pair rows rp and rp+8, cols 4*c4..+3
    const int rp = t / 80;         // 0..7
    const int c4 = t % 80;
    const int goff = 2 * rp * HW + 4 * c4;       // (c = 2rp, x = 4*c4)
    uint32_t* dstL = lds + rp * W + 4 * c4;
    uint32_t* dstR = dstL + MATD;

    float4 la0, la1, lb0, lb1, ra0, ra1, rb0, rb1;  // prefetch regs (32 VGPR)

    auto loadChunk = [&](int c0) {
        const float* Lp = Lg + baseLR + c0 * HW + goff;
        const float* Rp = Rg + baseLR + c0 * HW + goff;
        la0 = *(const float4*)(Lp);
        la1 = *(const float4*)(Lp + HW);
        lb0 = *(const float4*)(Lp + 16 * HW);
        lb1 = *(const float4*)(Lp + 17 * HW);
        ra0 = *(const float4*)(Rp);
        ra1 = *(const float4*)(Rp + HW);
        rb0 = *(const float4*)(Rp + 16 * HW);
        rb1 = *(const float4*)(Rp + 17 * HW);
    };

    auto writeLDS = [&]() {
        uint4 v;
        v.x = pack_bf16x2(la0.x, la1.x);
        v.y = pack_bf16x2(la0.y, la1.y);
        v.z = pack_bf16x2(la0.z, la1.z);
        v.w = pack_bf16x2(la0.w, la1.w);
        *reinterpret_cast<uint4*>(dstL) = v;
        v.x = pack_bf16x2(lb0.x, lb1.x);
        v.y = pack_bf16x2(lb0.y, lb1.y);
        v.z = pack_bf16x2(lb0.z, lb1.z);
        v.w = pack_bf16x2(lb0.w, lb1.w);
        *reinterpret_cast<uint4*>(dstL + 8 * W) = v;
        v.x = pack_bf16x2(ra0.x, ra1.x);
        v.y = pack_bf16x2(ra0.y, ra1.y);
        v.z = pack_bf16x2(ra0.z, ra1.z);
        v.w = pack_bf16x2(ra0.w, ra1.w);
        *reinterpret_cast<uint4*>(dstR) = v;
        v.x = pack_bf16x2(rb0.x, rb1.x);
        v.y = pack_bf16x2(rb0.y, rb1.y);
        v.z = pack_bf16x2(rb0.z, rb1.z);
        v.w = pack_bf16x2(rb0.w, rb1.w);
        *reinterpret_cast<uint4*>(dstR + 8 * W) = v;
    };

    floatx16 acc0 = 0.f, acc1 = 0.f, acc2 = 0.f;  // q = p, p-1, p-2

    loadChunk(0);
#pragma unroll
    for (int ck = 0; ck < 4; ++ck) {
        writeLDS();                 // waits vmcnt for prefetch regs
        __syncthreads();
        if (ck < 3) loadChunk((ck + 1) * KC);   // async: in flight over MFMA

        const uint32_t* sL = lds;
        const uint32_t* sR = lds + MATD;
#pragma unroll
        for (int ks = 0; ks < 2; ++ks) {
            const int pr = ks * 8 + half * 4;   // c-pair row base for this lane
            const uint32_t* pa = sL + pr * W + p * 32 + n;
            uint4 a4;
            a4.x = pa[0 * W]; a4.y = pa[1 * W]; a4.z = pa[2 * W]; a4.w = pa[3 * W];
            bf16x8 af = __builtin_bit_cast(bf16x8, a4);

            {
                const uint32_t* pb = sR + pr * W + p * 32 + n;
                uint4 b4;
                b4.x = pb[0 * W]; b4.y = pb[1 * W]; b4.z = pb[2 * W]; b4.w = pb[3 * W];
                acc0 = __builtin_amdgcn_mfma_f32_32x32x16_bf16(
                    af, __builtin_bit_cast(bf16x8, b4), acc0, 0, 0, 0);
            }
            if (p >= 1) {
                const uint32_t* pb = sR + pr * W + (p - 1) * 32 + n;
                uint4 b4;
                b4.x = pb[0 * W]; b4.y = pb[1 * W]; b4.z = pb[2 * W]; b4.w = pb[3 * W];
                acc1 = __builtin_amdgcn_mfma_f32_32x32x16_bf16(
                    af, __builtin_bit_cast(bf16x8, b4), acc1, 0, 0, 0);
            }
            if (p >= 2) {
                const uint32_t* pb = sR + pr * W + (p - 2) * 32 + n;
                uint4 b4;
                b4.x = pb[0 * W]; b4.y = pb[1 * W]; b4.z = pb[2 * W]; b4.w = pb[3 * W];
                acc2 = __builtin_amdgcn_mfma_f32_32x32x16_bf16(
                    af, __builtin_bit_cast(bf16x8, b4), acc2, 0, 0, 0);
            }
        }
        __syncthreads();
    }

    // ---- epilogue: 3 passes of 16 disparity rows, per-wave scratch ----
    // D layout (verified R1): m = (r&3) + 8*(r>>2) + 4*half, col = n
    float* sS = reinterpret_cast<float*>(lds) + p * (16 * 33);
    const int ob = b * (MAXD * HW) + h * W + p * 32;
    constexpr float scale = 1.f / 128.f;

#pragma unroll
    for (int pass = 0; pass < 3; ++pass) {
        const int r0 = pass * 16;
        if (p < 2) {  // only x<64 has an i>x zero triangle
#pragma unroll
            for (int e = 0; e < 9; ++e) {
                int idx = e * 64 + lane;
                if (idx < 16 * 33) sS[idx] = 0.f;
            }
        }
#define FILL_TILE(DP, ACC)                                                  \
        if (p >= (DP)) {                                                    \
            _Pragma("unroll")                                               \
            for (int r = 0; r < 16; ++r) {                                  \
                int m = (r & 3) + 8 * (r >> 2) + 4 * half;                  \
                int i = 32 * (DP) + m - n;                                  \
                if (i >= r0 && i < r0 + 16)                                 \
                    sS[(i - r0) * 33 + m] = ACC[r] * scale;                 \
            }                                                               \
        }
        FILL_TILE(0, acc0)
        FILL_TILE(1, acc1)
        FILL_TILE(2, acc2)
#undef FILL_TILE
#pragma unroll
        for (int e = 0; e < 8; ++e) {
            int idx = e * 64 + lane;
            int ii = idx >> 5;      // 0..15
            int m  = idx & 31;
            __builtin_nontemporal_store(sS[ii * 33 + m],
                                        &out[ob + (r0 + ii) * HW + m]);
        }
    }
}

extern "C" void kernel_launch(void* const* d_in, const int* in_sizes, int n_in,
                              void* d_out, int out_size, void* d_ws, size_t ws_size,
                              hipStream_t stream) {
    const float* L = (const float*)d_in[0];
    const float* R = (const float*)d_in[1];
    float* out = (float*)d_out;
    cost_volume_kernel<<<dim3(NB * H), dim3(640), 0, stream>>>(L, R, out);
}

// Round 3
// 413.823 us; speedup vs baseline: 1.0287x; 1.0287x over previous
//
#include <hip/hip_runtime.h>
#include <stdint.h>

// Cost volume = 48-wide band of Gram matrix L^T R per (b,h), K = c = 128.
// bf16 MFMA 32x32x16. Memory-bound target ~47us (298 MB @ 6.3 TB/s).
// R3: plain stores (NT caused 6x write amplification); double-buffered LDS
//     with soft barriers (lgkmcnt drain only, NO vmcnt drain) so prefetch
//     loads stay in flight across barriers -> break the device-wide convoy.

typedef __bf16 bf16x8 __attribute__((ext_vector_type(8)));
typedef float floatx16 __attribute__((ext_vector_type(16)));

constexpr int W = 320, H = 96, C = 128, NB = 8, MAXD = 48;
constexpr int HW = H * W;        // 30720
constexpr int MATD = 16 * W;     // dwords per staged matrix (16 c-pairs) = 5120
constexpr int BUFD = 2 * MATD;   // dwords per buffer (L+R) = 10240

__device__ __forceinline__ uint32_t pack_bf16x2(float a, float b) {
    // RNE f32->bf16; (c,x) low half, (c+1,x) high half == MFMA k-order.
    uint32_t ua = __float_as_uint(a), ub = __float_as_uint(b);
    uint32_t lo = (ua + 0x7fffu + ((ua >> 16) & 1u)) >> 16;
    uint32_t hi = (ub + 0x7fffu + ((ub >> 16) & 1u)) & 0xffff0000u;
    return hi | lo;
}

__device__ __forceinline__ void soft_barrier() {
    // Execution barrier + LDS visibility, WITHOUT the compiler's
    // vmcnt(0) drain -> global prefetch loads stay in flight across it.
    asm volatile("s_waitcnt lgkmcnt(0)" ::: "memory");
    __builtin_amdgcn_s_barrier();
    asm volatile("" ::: "memory");
}

__global__ __launch_bounds__(640, 5) void cost_volume_kernel(
    const float* __restrict__ Lg, const float* __restrict__ Rg,
    float* __restrict__ out)
{
    // 81920 B: two 40 KB staging buffers (bf16 [16 c-pairs][320] x {L,R}).
    // Reused by the epilogue scratch (10 waves * 48*33 f32 = 63360 B).
    __shared__ uint32_t lds[2 * BUFD];

    const int t    = threadIdx.x;
    const int lane = t & 63;
    const int p    = t >> 6;       // wave id = 32-wide x-tile id
    const int n    = lane & 31;
    const int half = lane >> 5;

    const int b = blockIdx.x / H;
    const int h = blockIdx.x % H;
    const int baseLR = b * (C * HW) + h * W;

    // staging unit: thread t covers c-pair rows rp and rp+8, cols 4*c4..+3
    const int rp = t / 80;         // 0..7
    const int c4 = t % 80;
    const int goff = 2 * rp * HW + 4 * c4;

    float4 la0, la1, lb0, lb1, ra0, ra1, rb0, rb1;  // prefetch regs (32 VGPR)

    auto loadChunk = [&](int c0) {
        const float* Lp = Lg + baseLR + c0 * HW + goff;
        const float* Rp = Rg + baseLR + c0 * HW + goff;
        la0 = *(const float4*)(Lp);
        la1 = *(const float4*)(Lp + HW);
        lb0 = *(const float4*)(Lp + 16 * HW);
        lb1 = *(const float4*)(Lp + 17 * HW);
        ra0 = *(const float4*)(Rp);
        ra1 = *(const float4*)(Rp + HW);
        rb0 = *(const float4*)(Rp + 16 * HW);
        rb1 = *(const float4*)(Rp + 17 * HW);
    };

    auto writeLDS = [&](uint32_t* buf) {
        uint32_t* dL = buf + rp * W + 4 * c4;
        uint32_t* dR = dL + MATD;
        uint4 v;
        v.x = pack_bf16x2(la0.x, la1.x);
        v.y = pack_bf16x2(la0.y, la1.y);
        v.z = pack_bf16x2(la0.z, la1.z);
        v.w = pack_bf16x2(la0.w, la1.w);
        *reinterpret_cast<uint4*>(dL) = v;
        v.x = pack_bf16x2(lb0.x, lb1.x);
        v.y = pack_bf16x2(lb0.y, lb1.y);
        v.z = pack_bf16x2(lb0.z, lb1.z);
        v.w = pack_bf16x2(lb0.w, lb1.w);
        *reinterpret_cast<uint4*>(dL + 8 * W) = v;
        v.x = pack_bf16x2(ra0.x, ra1.x);
        v.y = pack_bf16x2(ra0.y, ra1.y);
        v.z = pack_bf16x2(ra0.z, ra1.z);
        v.w = pack_bf16x2(ra0.w, ra1.w);
        *reinterpret_cast<uint4*>(dR) = v;
        v.x = pack_bf16x2(rb0.x, rb1.x);
        v.y = pack_bf16x2(rb0.y, rb1.y);
        v.z = pack_bf16x2(rb0.z, rb1.z);
        v.w = pack_bf16x2(rb0.w, rb1.w);
        *reinterpret_cast<uint4*>(dR + 8 * W) = v;
    };

    floatx16 acc0 = 0.f, acc1 = 0.f, acc2 = 0.f;  // q = p, p-1, p-2

    loadChunk(0);
    writeLDS(lds);            // buf0 <- chunk0
    loadChunk(32);            // chunk1 in flight across the barrier
    soft_barrier();

#pragma unroll
    for (int ck = 0; ck < 4; ++ck) {
        const uint32_t* sL = lds + (ck & 1) * BUFD;
        const uint32_t* sR = sL + MATD;
        uint32_t* nxt = lds + ((ck + 1) & 1) * BUFD;

#pragma unroll
        for (int ks = 0; ks < 2; ++ks) {
            const int pr = ks * 8 + half * 4;   // c-pair row base for this lane
            const uint32_t* pa = sL + pr * W + p * 32 + n;
            uint4 a4;
            a4.x = pa[0 * W]; a4.y = pa[1 * W]; a4.z = pa[2 * W]; a4.w = pa[3 * W];
            bf16x8 af = __builtin_bit_cast(bf16x8, a4);

            {
                const uint32_t* pb = sR + pr * W + p * 32 + n;
                uint4 b4;
                b4.x = pb[0 * W]; b4.y = pb[1 * W]; b4.z = pb[2 * W]; b4.w = pb[3 * W];
                acc0 = __builtin_amdgcn_mfma_f32_32x32x16_bf16(
                    af, __builtin_bit_cast(bf16x8, b4), acc0, 0, 0, 0);
            }
            if (p >= 1) {
                const uint32_t* pb = sR + pr * W + (p - 1) * 32 + n;
                uint4 b4;
                b4.x = pb[0 * W]; b4.y = pb[1 * W]; b4.z = pb[2 * W]; b4.w = pb[3 * W];
                acc1 = __builtin_amdgcn_mfma_f32_32x32x16_bf16(
                    af, __builtin_bit_cast(bf16x8, b4), acc1, 0, 0, 0);
            }
            if (p >= 2) {
                const uint32_t* pb = sR + pr * W + (p - 2) * 32 + n;
                uint4 b4;
                b4.x = pb[0 * W]; b4.y = pb[1 * W]; b4.z = pb[2 * W]; b4.w = pb[3 * W];
                acc2 = __builtin_amdgcn_mfma_f32_32x32x16_bf16(
                    af, __builtin_bit_cast(bf16x8, b4), acc2, 0, 0, 0);
            }
        }

        // consume chunk ck+1 regs into the other buffer, then issue chunk
        // ck+2 loads -> they stay outstanding through the soft barrier and
        // the whole next MFMA phase (no vmcnt drain at the barrier).
        if (ck < 3) writeLDS(nxt);
        if (ck < 2) loadChunk((ck + 2) * 32);
        soft_barrier();
    }

    __syncthreads();   // one full drain before reusing LDS as scratch

    // ---- epilogue: band -> per-wave LDS transpose -> coalesced stores ----
    // D layout (verified): m = (r&3) + 8*(r>>2) + 4*half, col = n
    float* sS = reinterpret_cast<float*>(lds) + p * (MAXD * 33);
    const int ob = b * (MAXD * HW) + h * W + p * 32;
    constexpr float scale = 1.f / 128.f;

    if (p < 2) {  // only x<64 has an i>x zero triangle
        for (int e = lane; e < MAXD * 33; e += 64) sS[e] = 0.f;
    }

#define FILL_TILE(DP, ACC)                                                  \
    if (p >= (DP)) {                                                        \
        _Pragma("unroll")                                                   \
        for (int r = 0; r < 16; ++r) {                                      \
            int m = (r & 3) + 8 * (r >> 2) + 4 * half;                      \
            int i = 32 * (DP) + m - n;                                      \
            if (i >= 0 && i < MAXD)                                         \
                sS[i * 33 + m] = ACC[r] * scale;                            \
        }                                                                   \
    }
    FILL_TILE(0, acc0)
    FILL_TILE(1, acc1)
    FILL_TILE(2, acc2)
#undef FILL_TILE

#pragma unroll
    for (int e = 0; e < 24; ++e) {
        int idx = e * 64 + lane;
        int i = idx >> 5;        // disparity 0..47
        int m = idx & 31;        // x-local
        out[ob + i * HW + m] = sS[i * 33 + m];
    }
}

extern "C" void kernel_launch(void* const* d_in, const int* in_sizes, int n_in,
                              void* d_out, int out_size, void* d_ws, size_t ws_size,
                              hipStream_t stream) {
    const float* L = (const float*)d_in[0];
    const float* R = (const float*)d_in[1];
    float* out = (float*)d_out;
    cost_volume_kernel<<<dim3(NB * H), dim3(640), 0, stream>>>(L, R, out);
}

// Round 4
// 274.075 us; speedup vs baseline: 1.5532x; 1.5099x over previous
//
#include <hip/hip_runtime.h>
#include <stdint.h>

// Cost volume = 48-wide band of Gram matrix L^T R per (b,h), K = c = 128.
// bf16 MFMA 32x32x16. Memory-bound target ~47us (298 MB @ 6.3 TB/s).
// R4: fix register spill (launch_bounds(640,5) => 96 unified regs/wave;
//     48 AGPR accum + slim 16-VGPR prefetch must fit). 16-c-row stages,
//     8 stages, double-buffered LDS, soft barriers (no vmcnt drain).

typedef __bf16 bf16x8 __attribute__((ext_vector_type(8)));
typedef float floatx16 __attribute__((ext_vector_type(16)));

constexpr int W = 320, H = 96, C = 128, NB = 8, MAXD = 48;
constexpr int HW = H * W;        // 30720
constexpr int SC = 16;           // c-rows per stage
constexpr int MATD = 8 * W;      // packed dwords per matrix per stage = 2560
constexpr int BUFD = 2 * MATD;   // dwords per buffer (L+R) = 5120 (20 KB)
constexpr int NST = C / SC;      // 8 stages

__device__ __forceinline__ uint32_t pack_bf16x2(float a, float b) {
    // RNE f32->bf16; (c even -> low16, c odd -> high16) == MFMA k-order.
    uint32_t ua = __float_as_uint(a), ub = __float_as_uint(b);
    uint32_t lo = (ua + 0x7fffu + ((ua >> 16) & 1u)) >> 16;
    uint32_t hi = (ub + 0x7fffu + ((ub >> 16) & 1u)) & 0xffff0000u;
    return hi | lo;
}

__device__ __forceinline__ void soft_barrier() {
    // Execution barrier + LDS visibility WITHOUT vmcnt(0) drain:
    // global prefetch loads stay in flight across it.
    asm volatile("s_waitcnt lgkmcnt(0)" ::: "memory");
    __builtin_amdgcn_s_barrier();
    asm volatile("" ::: "memory");
}

__global__ __launch_bounds__(640, 5) void cost_volume_kernel(
    const float* __restrict__ Lg, const float* __restrict__ Rg,
    float* __restrict__ out)
{
    // 63360 B: two 20 KB stage buffers (10240 dwords) overlapped with the
    // epilogue scratch (10 waves * 48*33 f32 = 15840 dwords).
    __shared__ uint32_t lds[15840];

    const int t    = threadIdx.x;
    const int lane = t & 63;
    const int p    = t >> 6;       // wave id = 32-wide x-tile id
    const int n    = lane & 31;
    const int half = lane >> 5;

    const int b = blockIdx.x / H;
    const int h = blockIdx.x % H;
    const int baseLR = b * (C * HW) + h * W;

    // staging: thread t covers c-pair row rp (c = 2rp, 2rp+1), cols 4*c4..+3
    const int rp = t / 80;         // 0..7
    const int c4 = t % 80;
    const float* Lt = Lg + baseLR + 2 * rp * HW + 4 * c4;
    const float* Rt = Rg + baseLR + 2 * rp * HW + 4 * c4;

    float4 l0, l1, r0, r1;         // prefetch regs (16 VGPR)

    auto loadStage = [&](int s) {
        const float* Lp = Lt + s * SC * HW;
        const float* Rp = Rt + s * SC * HW;
        l0 = *(const float4*)(Lp);
        l1 = *(const float4*)(Lp + HW);
        r0 = *(const float4*)(Rp);
        r1 = *(const float4*)(Rp + HW);
    };

    auto writeLDS = [&](uint32_t* buf) {
        uint32_t* d = buf + rp * W + 4 * c4;
        uint4 v;
        v.x = pack_bf16x2(l0.x, l1.x);
        v.y = pack_bf16x2(l0.y, l1.y);
        v.z = pack_bf16x2(l0.z, l1.z);
        v.w = pack_bf16x2(l0.w, l1.w);
        *reinterpret_cast<uint4*>(d) = v;
        v.x = pack_bf16x2(r0.x, r1.x);
        v.y = pack_bf16x2(r0.y, r1.y);
        v.z = pack_bf16x2(r0.z, r1.z);
        v.w = pack_bf16x2(r0.w, r1.w);
        *reinterpret_cast<uint4*>(d + MATD) = v;
    };

    floatx16 acc0 = 0.f, acc1 = 0.f, acc2 = 0.f;  // q = p, p-1, p-2

    loadStage(0);
    writeLDS(lds);            // buf0 <- stage 0 (vmcnt waits via dependency)
    loadStage(1);             // stage 1 in flight across the barrier
    soft_barrier();

#pragma unroll 1
    for (int s = 0; s < NST; ++s) {
        const uint32_t* sL = lds + (s & 1) * BUFD;
        const uint32_t* sR = sL + MATD;

        // A fragment: k = half*8 + j -> c-pair rows half*4 + jj
        const uint32_t* pa = sL + half * 4 * W + p * 32 + n;
        uint4 a4;
        a4.x = pa[0 * W]; a4.y = pa[1 * W]; a4.z = pa[2 * W]; a4.w = pa[3 * W];
        bf16x8 af = __builtin_bit_cast(bf16x8, a4);

        {
            const uint32_t* pb = sR + half * 4 * W + p * 32 + n;
            uint4 b4;
            b4.x = pb[0 * W]; b4.y = pb[1 * W]; b4.z = pb[2 * W]; b4.w = pb[3 * W];
            acc0 = __builtin_amdgcn_mfma_f32_32x32x16_bf16(
                af, __builtin_bit_cast(bf16x8, b4), acc0, 0, 0, 0);
        }
        if (p >= 1) {
            const uint32_t* pb = sR + half * 4 * W + (p - 1) * 32 + n;
            uint4 b4;
            b4.x = pb[0 * W]; b4.y = pb[1 * W]; b4.z = pb[2 * W]; b4.w = pb[3 * W];
            acc1 = __builtin_amdgcn_mfma_f32_32x32x16_bf16(
                af, __builtin_bit_cast(bf16x8, b4), acc1, 0, 0, 0);
        }
        if (p >= 2) {
            const uint32_t* pb = sR + half * 4 * W + (p - 2) * 32 + n;
            uint4 b4;
            b4.x = pb[0 * W]; b4.y = pb[1 * W]; b4.z = pb[2 * W]; b4.w = pb[3 * W];
            acc2 = __builtin_amdgcn_mfma_f32_32x32x16_bf16(
                af, __builtin_bit_cast(bf16x8, b4), acc2, 0, 0, 0);
        }

        // consume stage s+1 regs into the other buffer, then issue stage
        // s+2 loads -> outstanding through the soft barrier + next MFMAs.
        if (s < NST - 1) writeLDS(lds + ((s + 1) & 1) * BUFD);
        if (s < NST - 2) loadStage(s + 2);
        soft_barrier();
    }

    __syncthreads();   // full drain before reusing LDS as scratch

    // ---- epilogue: band -> per-wave LDS transpose -> coalesced stores ----
    // D layout (verified): m = (r&3) + 8*(r>>2) + 4*half, col = n
    float* sS = reinterpret_cast<float*>(lds) + p * (MAXD * 33);
    const int ob = b * (MAXD * HW) + h * W + p * 32;
    constexpr float scale = 1.f / 128.f;

    if (p < 2) {  // only x<64 has an i>x zero triangle
        for (int e = lane; e < MAXD * 33; e += 64) sS[e] = 0.f;
    }

#define FILL_TILE(DP, ACC)                                                  \
    if (p >= (DP)) {                                                        \
        _Pragma("unroll")                                                   \
        for (int r = 0; r < 16; ++r) {                                      \
            int m = (r & 3) + 8 * (r >> 2) + 4 * half;                      \
            int i = 32 * (DP) + m - n;                                      \
            if (i >= 0 && i < MAXD)                                         \
                sS[i * 33 + m] = ACC[r] * scale;                            \
        }                                                                   \
    }
    FILL_TILE(0, acc0)
    FILL_TILE(1, acc1)
    FILL_TILE(2, acc2)
#undef FILL_TILE

#pragma unroll
    for (int e = 0; e < 24; ++e) {
        int idx = e * 64 + lane;
        int i = idx >> 5;        // disparity 0..47
        int m = idx & 31;        // x-local
        out[ob + i * HW + m] = sS[i * 33 + m];
    }
}

extern "C" void kernel_launch(void* const* d_in, const int* in_sizes, int n_in,
                              void* d_out, int out_size, void* d_ws, size_t ws_size,
                              hipStream_t stream) {
    const float* L = (const float*)d_in[0];
    const float* R = (const float*)d_in[1];
    float* out = (float*)d_out;
    cost_volume_kernel<<<dim3(NB * H), dim3(640), 0, stream>>>(L, R, out);
}